// Round 11
// baseline (191.227 us; speedup 1.0000x reference)
//
#include <hip/hip_runtime.h>
#include <hip/hip_bf16.h>
#include <math.h>

#define DD 256
#define LN_EPS 1e-5f
#define BKT 128     // fixed bucket slots per destination node (P(deg>128) ~ 0 at E/N=32)
#define EPB 2048    // edges per stage-1 block
#define NPM 256     // max partitions supported (N_ <= 32768); partition = dst >> 7

typedef unsigned short u16;
typedef __attribute__((ext_vector_type(8))) short short8;
typedef __attribute__((ext_vector_type(4))) float floatx4;

__device__ __forceinline__ u16 f2b(float f) {
    __hip_bfloat16 h = __float2bfloat16(f);
    return *reinterpret_cast<u16*>(&h);
}
__device__ __forceinline__ float b2f(unsigned int u) {
    union { unsigned int i; float f; } x;
    x.i = u << 16;
    return x.f;
}

// ---------------- fused preamble: edge partition-sort stage1 | weight transpose+bf16 | LN1 ----

__global__ void __launch_bounds__(256) k_pre(
    const float* __restrict__ Wq, const float* __restrict__ Wk,
    const float* __restrict__ Wv, const float* __restrict__ Wo,
    u16* __restrict__ Wt,
    const float* __restrict__ x, const float* __restrict__ g1, const float* __restrict__ b1,
    int N_, u16* __restrict__ xn,
    const int* __restrict__ src, const int* __restrict__ dst, int E_,
    unsigned* __restrict__ stageE, int* __restrict__ stageI, int nb1) {
    int b = blockIdx.x;
    int t = threadIdx.x;

    if (b < nb1) {                      // ---- stage 1: partition-group edges ----
        __shared__ int h[NPM];
        __shared__ int hs[NPM];
        __shared__ int h2[NPM];
        int e0 = b * EPB;
        int ecnt = E_ - e0; if (ecnt > EPB) ecnt = EPB;
        if (t < NPM) h[t] = 0;
        __syncthreads();
        for (int i = t; i < ecnt; i += 256) {
            int d = dst[e0 + i];
            atomicAdd(&h[d >> 7], 1);           // LDS atomic
        }
        __syncthreads();
        if (t < NPM) hs[t] = h[t];
        __syncthreads();
        for (int off = 1; off < NPM; off <<= 1) {   // Hillis-Steele inclusive scan
            int add = 0;
            if (t < NPM && t >= off) add = hs[t - off];
            __syncthreads();
            if (t < NPM) hs[t] += add;
            __syncthreads();
        }
        if (t < NPM) {
            int ex = hs[t] - h[t];              // exclusive prefix
            h2[t] = ex;
            stageI[b * (NPM + 1) + t] = ex;
            if (t == NPM - 1) stageI[b * (NPM + 1) + NPM] = hs[t];
        }
        __syncthreads();
        for (int i = t; i < ecnt; i += 256) {
            int d = dst[e0 + i];
            int s = src[e0 + i];
            int p = d >> 7;
            int slot = atomicAdd(&h2[p], 1);    // LDS atomic
            int dl = d & 127;
            stageE[(size_t)b * EPB + slot] = (unsigned)((dl << 16) | s);
        }
        return;
    }
    if (b < nb1 + 64) {                 // ---- weight transpose + bf16 convert ----
        __shared__ float tile[64][65];
        int bb = b - nb1;
        int k0 = (bb & 3) * 64;
        int n0 = (bb >> 2) * 64;
        int sel = n0 >> 8;
        const float* W = (sel == 0) ? Wq : (sel == 1) ? Wk : (sel == 2) ? Wv : Wo;
        int ncol0 = n0 & 255;
#pragma unroll
        for (int p = 0; p < 16; p++) {
            int kk = p * 4 + (t >> 6);
            int nn = t & 63;
            tile[kk][nn] = W[(size_t)(k0 + kk) * DD + ncol0 + nn];
        }
        __syncthreads();
#pragma unroll
        for (int p = 0; p < 16; p++) {
            int nn = p * 4 + (t >> 6);
            int kk = t & 63;
            Wt[(size_t)(n0 + nn) * DD + k0 + kk] = f2b(tile[kk][nn]);
        }
        return;
    }
    // ---- LN1: wave per node ----
    int lane = t & 63;
    int node = (b - nb1 - 64) * 4 + (t >> 6);
    if (node >= N_) return;
    size_t base = (size_t)node * DD + lane * 4;
    float4 xv = *(const float4*)&x[base];
    float s = xv.x + xv.y + xv.z + xv.w;
    s += __shfl_xor(s, 1); s += __shfl_xor(s, 2); s += __shfl_xor(s, 4);
    s += __shfl_xor(s, 8); s += __shfl_xor(s, 16); s += __shfl_xor(s, 32);
    float mean = s * (1.f / DD);
    float d0 = xv.x - mean, d1 = xv.y - mean, d2 = xv.z - mean, d3 = xv.w - mean;
    float v = d0 * d0 + d1 * d1 + d2 * d2 + d3 * d3;
    v += __shfl_xor(v, 1); v += __shfl_xor(v, 2); v += __shfl_xor(v, 4);
    v += __shfl_xor(v, 8); v += __shfl_xor(v, 16); v += __shfl_xor(v, 32);
    float rstd = rsqrtf(v * (1.f / DD) + LN_EPS);
    float4 gv = *(const float4*)&g1[lane * 4];
    float4 bv = *(const float4*)&b1[lane * 4];
    uint2 o;
    o.x = (unsigned)f2b(d0 * rstd * gv.x + bv.x) | ((unsigned)f2b(d1 * rstd * gv.y + bv.y) << 16);
    o.y = (unsigned)f2b(d2 * rstd * gv.z + bv.z) | ((unsigned)f2b(d3 * rstd * gv.w + bv.w) << 16);
    *(uint2*)&xn[base] = o;
}

// ---------------- merged: stage-2 bucketize (LDS atomics only) | QKV GEMM ----------------
// khv layout (bf16), per-head INTERLEAVED k/v (r7 layout — best measured):
//   khv[(h*N + node)*128 + (dim>>2)*8 + (dim&3) + (v? 4:0)]
// Per-head block = 2.56MB -> XCD-L2 resident. q stays f32 with 1/sqrt(64) folded.
// Buckets PADDED to a multiple of 32 entries with index 0 (masked by deg in k_attn).

__global__ void __launch_bounds__(256) k_mid(
    const unsigned* __restrict__ stageE, const int* __restrict__ stageI, int nb1, int np,
    int* __restrict__ cnt, int* __restrict__ bkt,
    const u16* __restrict__ xn, const u16* __restrict__ Wt,
    const float* __restrict__ bq, const float* __restrict__ bk, const float* __restrict__ bv,
    int N_, float* __restrict__ q, u16* __restrict__ khv, int E_) {
    int b = blockIdx.x;
    int t = threadIdx.x;

    if (b < np) {                       // ---- stage 2: bucketize partition b ----
        __shared__ int lcnt[128];
        if (t < 128) lcnt[t] = 0;
        __syncthreads();
        int node0 = b << 7;
        for (int bb = t; bb < nb1; bb += 256) {
            int beg = stageI[bb * (NPM + 1) + b];
            int end = stageI[bb * (NPM + 1) + b + 1];
            const unsigned* se = stageE + (size_t)bb * EPB;
            for (int i = beg; i < end; i++) {
                unsigned v = se[i];
                int dl = v >> 16;
                int s = v & 0xffff;
                int sl = atomicAdd(&lcnt[dl], 1);   // LDS atomic
                if (sl < BKT) bkt[(size_t)(node0 + dl) * BKT + sl] = s;
            }
        }
        __syncthreads();
        if (t < 128) {
            int node = node0 + t;
            if (node < N_) {
                int c = lcnt[t]; if (c > BKT) c = BKT;
                cnt[node] = lcnt[t];
                int cap = (c + 31) & ~31; if (cap > BKT) cap = BKT;
                for (int i = c; i < cap; i++)       // pad to mult-of-32 (masked by deg)
                    bkt[(size_t)node * BKT + i] = 0;
            }
        }
        return;
    }

    // ---- QKV GEMM: 64-row x 256-col blocks (kind=q/k/v), wave = one head's 64 cols ----
    int bq_ = b - np;
    int nxb = (N_ + 63) / 64;
    int bx = bq_ % nxb, kind = bq_ / nxb;   // kind: 0=q, 1=k, 2=v
    int w = t >> 6, lane = t & 63;
    int li = lane & 15, quad = lane >> 4;
    int m0 = bx * 64;
    int ncol0 = kind * 256 + w * 64;

    floatx4 acc[4][4];
#pragma unroll
    for (int mi = 0; mi < 4; mi++)
#pragma unroll
        for (int nf = 0; nf < 4; nf++) acc[mi][nf] = (floatx4){0.f, 0.f, 0.f, 0.f};

    const u16* A[4];
#pragma unroll
    for (int mi = 0; mi < 4; mi++) {
        int r = m0 + mi * 16 + li;
        if (r > N_ - 1) r = N_ - 1;
        A[mi] = xn + (size_t)r * DD;
    }
    const u16* B0 = Wt + (size_t)(ncol0 + li) * DD;

    short8 a[4], bb[4];
    int ko = quad * 8;
#pragma unroll
    for (int mi = 0; mi < 4; mi++) a[mi] = *(const short8*)&A[mi][ko];
#pragma unroll
    for (int nf = 0; nf < 4; nf++) bb[nf] = *(const short8*)&B0[(size_t)nf * 16 * DD + ko];

    for (int kk = 0; kk < 8; kk++) {
        short8 an[4], bn[4];
        if (kk < 7) {
            int kon = (kk + 1) * 32 + quad * 8;
#pragma unroll
            for (int mi = 0; mi < 4; mi++) an[mi] = *(const short8*)&A[mi][kon];
#pragma unroll
            for (int nf = 0; nf < 4; nf++) bn[nf] = *(const short8*)&B0[(size_t)nf * 16 * DD + kon];
        }
#pragma unroll
        for (int nf = 0; nf < 4; nf++)
#pragma unroll
            for (int mi = 0; mi < 4; mi++)
                acc[mi][nf] = __builtin_amdgcn_mfma_f32_16x16x32_bf16(a[mi], bb[nf], acc[mi][nf], 0, 0, 0);
        if (kk < 7) {
#pragma unroll
            for (int mi = 0; mi < 4; mi++) a[mi] = an[mi];
#pragma unroll
            for (int nf = 0; nf < 4; nf++) bb[nf] = bn[nf];
        }
    }

    // epilogue: q f32 (0.125 folded); k/v interleaved bf16
#pragma unroll
    for (int nf = 0; nf < 4; nf++) {
        int c = ncol0 + nf * 16 + li;            // global col
        float bias;
        if (kind == 0)      bias = bq[c];
        else if (kind == 1) bias = bk[c - 256];
        else                bias = bv[c - 512];
        int cc = (kind == 0) ? c : (c - (kind == 1 ? 256 : 512));  // 0..255
        int h = cc >> 6, dim = cc & 63;
#pragma unroll
        for (int mi = 0; mi < 4; mi++) {
#pragma unroll
            for (int r = 0; r < 4; r++) {
                int row = m0 + mi * 16 + quad * 4 + r;
                if (row >= N_) continue;
                float val = acc[mi][nf][r] + bias;
                if (kind == 0) {
                    q[(size_t)row * DD + c] = val * 0.125f;  // fold 1/sqrt(64)
                } else {
                    size_t idx = ((size_t)h * N_ + row) * 128
                               + (dim >> 2) * 8 + (dim & 3) + (kind == 2 ? 4 : 0);
                    khv[idx] = f2b(val);
                }
            }
        }
    }
}

// ---------------- attention: head-split + XCD-pinned, TWO nodes/wave (dual chains) ----
// r7 structure + intra-wave ILP: each wave owns 2 nodes = 2 INDEPENDENT
// index->gather->compute recurrences. Node A's gather latency hides under node
// B's score/PV compute (r10 lesson: deepening ONE chain's window is neutral —
// the serial recurrence itself is the limit; overlap needs independent chains).
// 16-edge windows per node, 8 gathers outstanding across the two chains,
// per-node wave-uniform guards. block b: XCD = b%8, head h = (b&7)>>1 (L2 pin).
// Grid = ceil(N/16)*8 x 4 waves = 20000 waves (2.4x capacity).

__global__ void __launch_bounds__(256) k_attn(
    const float* __restrict__ q, const u16* __restrict__ khv,
    const int* __restrict__ cnt, const int* __restrict__ bkt,
    int N_, u16* __restrict__ agg) {
    int t = threadIdx.x;
    int w = t >> 6, lane = t & 63;
    int li = lane & 15, quad = lane >> 4;
    int b = blockIdx.x;
    int g = b >> 3;
    int h = (b & 7) >> 1;
    int sub = b & 1;
    int node0 = g * 16 + sub * 8 + w * 2;
    if (node0 >= N_) return;
    int node1 = node0 + 1;
    bool has1 = node1 < N_;
    const u16* kvh = khv + (size_t)h * N_ * 128;
    size_t kvoff = (size_t)li * 8;

    int deg0 = cnt[node0]; if (deg0 > BKT) deg0 = BKT;
    int deg1 = has1 ? cnt[node1] : 0; if (deg1 > BKT) deg1 = BKT;

    const int* eb0 = bkt + (size_t)node0 * BKT;
    const int* eb1 = bkt + (size_t)node1 * BKT;
    float4 qv0 = *(const float4*)&q[(size_t)node0 * DD + h * 64 + li * 4];
    float4 qv1 = qv0;
    if (deg1 > 0) qv1 = *(const float4*)&q[(size_t)node1 * DD + h * 64 + li * 4];

    float l0 = 0.f, a00 = 0.f, a01 = 0.f, a02 = 0.f, a03 = 0.f;
    float l1 = 0.f, a10 = 0.f, a11 = 0.f, a12 = 0.f, a13 = 0.f;

    int4 s0, s1;
    s0.x = s0.y = s0.z = s0.w = 0;
    s1 = s0;
    if (deg0 > 0) s0 = *(const int4*)&eb0[quad * 4];   // padded -> always valid
    if (deg1 > 0) s1 = *(const int4*)&eb1[quad * 4];

    int dmax = deg0 > deg1 ? deg0 : deg1;
    for (int e = 0; e < dmax; e += 16) {
        bool g0 = e < deg0, g1 = e < deg1;   // wave-uniform
        uint4 p0[4], p1[4];
        if (g0) {
            p0[0] = *(const uint4*)&kvh[(size_t)s0.x * 128 + kvoff];
            p0[1] = *(const uint4*)&kvh[(size_t)s0.y * 128 + kvoff];
            p0[2] = *(const uint4*)&kvh[(size_t)s0.z * 128 + kvoff];
            p0[3] = *(const uint4*)&kvh[(size_t)s0.w * 128 + kvoff];
        }
        if (g1) {
            p1[0] = *(const uint4*)&kvh[(size_t)s1.x * 128 + kvoff];
            p1[1] = *(const uint4*)&kvh[(size_t)s1.y * 128 + kvoff];
            p1[2] = *(const uint4*)&kvh[(size_t)s1.z * 128 + kvoff];
            p1[3] = *(const uint4*)&kvh[(size_t)s1.w * 128 + kvoff];
        }
        int en = e + 16;
        if (en < deg0) s0 = *(const int4*)&eb0[en + quad * 4];
        if (en < deg1) s1 = *(const int4*)&eb1[en + quad * 4];

        if (g0) {
#pragma unroll
            for (int d = 0; d < 4; d++) {
                bool valid = (e + quad * 4 + d) < deg0;
                float s = qv0.x * b2f(p0[d].x & 0xffff) + qv0.y * b2f(p0[d].x >> 16)
                        + qv0.z * b2f(p0[d].y & 0xffff) + qv0.w * b2f(p0[d].y >> 16);
                s += __shfl_xor(s, 1); s += __shfl_xor(s, 2);
                s += __shfl_xor(s, 4); s += __shfl_xor(s, 8);
                float pe = valid ? __expf(s) : 0.f;
                l0 += pe;
                a00 += pe * b2f(p0[d].z & 0xffff);
                a01 += pe * b2f(p0[d].z >> 16);
                a02 += pe * b2f(p0[d].w & 0xffff);
                a03 += pe * b2f(p0[d].w >> 16);
            }
        }
        if (g1) {
#pragma unroll
            for (int d = 0; d < 4; d++) {
                bool valid = (e + quad * 4 + d) < deg1;
                float s = qv1.x * b2f(p1[d].x & 0xffff) + qv1.y * b2f(p1[d].x >> 16)
                        + qv1.z * b2f(p1[d].y & 0xffff) + qv1.w * b2f(p1[d].y >> 16);
                s += __shfl_xor(s, 1); s += __shfl_xor(s, 2);
                s += __shfl_xor(s, 4); s += __shfl_xor(s, 8);
                float pe = valid ? __expf(s) : 0.f;
                l1 += pe;
                a10 += pe * b2f(p1[d].z & 0xffff);
                a11 += pe * b2f(p1[d].z >> 16);
                a12 += pe * b2f(p1[d].w & 0xffff);
                a13 += pe * b2f(p1[d].w >> 16);
            }
        }
    }

    // reduce over quad (lanes ^16, ^32) and store, per node
    l0  += __shfl_xor(l0, 16);  l0  += __shfl_xor(l0, 32);
    a00 += __shfl_xor(a00, 16); a00 += __shfl_xor(a00, 32);
    a01 += __shfl_xor(a01, 16); a01 += __shfl_xor(a01, 32);
    a02 += __shfl_xor(a02, 16); a02 += __shfl_xor(a02, 32);
    a03 += __shfl_xor(a03, 16); a03 += __shfl_xor(a03, 32);
    if (quad == 0) {
        uint2 o; o.x = 0u; o.y = 0u;
        if (deg0 > 0) {
            float invl = 1.f / l0;
            o.x = (unsigned)f2b(a00 * invl) | ((unsigned)f2b(a01 * invl) << 16);
            o.y = (unsigned)f2b(a02 * invl) | ((unsigned)f2b(a03 * invl) << 16);
        }
        *(uint2*)(agg + (size_t)node0 * DD + h * 64 + li * 4) = o;
    }
    if (has1) {
        l1  += __shfl_xor(l1, 16);  l1  += __shfl_xor(l1, 32);
        a10 += __shfl_xor(a10, 16); a10 += __shfl_xor(a10, 32);
        a11 += __shfl_xor(a11, 16); a11 += __shfl_xor(a11, 32);
        a12 += __shfl_xor(a12, 16); a12 += __shfl_xor(a12, 32);
        a13 += __shfl_xor(a13, 16); a13 += __shfl_xor(a13, 32);
        if (quad == 0) {
            uint2 o; o.x = 0u; o.y = 0u;
            if (deg1 > 0) {
                float invl = 1.f / l1;
                o.x = (unsigned)f2b(a10 * invl) | ((unsigned)f2b(a11 * invl) << 16);
                o.y = (unsigned)f2b(a12 * invl) | ((unsigned)f2b(a13 * invl) << 16);
            }
            *(uint2*)(agg + (size_t)node1 * DD + h * 64 + li * 4) = o;
        }
    }
}

// ---------------- out-GEMM + LN2 + relu + residual: 16 rows/block ----------------

__global__ void __launch_bounds__(256) k_out(
    const u16* __restrict__ agg, const u16* __restrict__ Wt, const float* __restrict__ bo,
    const float* __restrict__ g2, const float* __restrict__ b2,
    const float* __restrict__ x, int N_, float* __restrict__ out) {
    __shared__ float wsum[4][16];
    __shared__ float wvar[4][16];
    int t = threadIdx.x;
    int w = t >> 6, lane = t & 63;
    int li = lane & 15, quad = lane >> 4;
    int m0 = blockIdx.x * 16;

    int ar = m0 + li; if (ar > N_ - 1) ar = N_ - 1;
    const u16* A0 = agg + (size_t)ar * DD;
    const u16* B0 = Wt + (size_t)(768 + w * 64 + li) * DD;

    floatx4 acc[4];
#pragma unroll
    for (int nf = 0; nf < 4; nf++) acc[nf] = (floatx4){0.f, 0.f, 0.f, 0.f};

#pragma unroll 2
    for (int kk = 0; kk < 8; kk++) {
        int ko = kk * 32 + quad * 8;
        short8 a = *(const short8*)&A0[ko];
#pragma unroll
        for (int nf = 0; nf < 4; nf++) {
            short8 bfrag = *(const short8*)&B0[(size_t)nf * 16 * DD + ko];
            acc[nf] = __builtin_amdgcn_mfma_f32_16x16x32_bf16(a, bfrag, acc[nf], 0, 0, 0);
        }
    }

#pragma unroll
    for (int nf = 0; nf < 4; nf++) {
        float bb = bo[w * 64 + nf * 16 + li];
#pragma unroll
        for (int r = 0; r < 4; r++) acc[nf][r] += bb;
    }

    // LN2: per-row partial sums over this wave's 64 cols, then cross-wave via LDS
#pragma unroll
    for (int r = 0; r < 4; r++) {
        float s = acc[0][r] + acc[1][r] + acc[2][r] + acc[3][r];
        s += __shfl_xor(s, 1); s += __shfl_xor(s, 2);
        s += __shfl_xor(s, 4); s += __shfl_xor(s, 8);
        if (li == 0) wsum[w][quad * 4 + r] = s;
    }
    __syncthreads();
    float mean[4];
#pragma unroll
    for (int r = 0; r < 4; r++) {
        int rl = quad * 4 + r;
        mean[r] = (wsum[0][rl] + wsum[1][rl] + wsum[2][rl] + wsum[3][rl]) * (1.f / DD);
    }
#pragma unroll
    for (int r = 0; r < 4; r++) {
        float vs = 0.f;
#pragma unroll
        for (int nf = 0; nf < 4; nf++) {
            float d = acc[nf][r] - mean[r];
            vs += d * d;
        }
        vs += __shfl_xor(vs, 1); vs += __shfl_xor(vs, 2);
        vs += __shfl_xor(vs, 4); vs += __shfl_xor(vs, 8);
        if (li == 0) wvar[w][quad * 4 + r] = vs;
    }
    __syncthreads();
    float rstd[4];
#pragma unroll
    for (int r = 0; r < 4; r++) {
        int rl = quad * 4 + r;
        rstd[r] = rsqrtf((wvar[0][rl] + wvar[1][rl] + wvar[2][rl] + wvar[3][rl]) * (1.f / DD) + LN_EPS);
    }

#pragma unroll
    for (int nf = 0; nf < 4; nf++) {
        int col = w * 64 + nf * 16 + li;
        float gv = g2[col], bv2 = b2[col];
#pragma unroll
        for (int r = 0; r < 4; r++) {
            int row = m0 + quad * 4 + r;
            if (row >= N_) continue;
            float y = (acc[nf][r] - mean[r]) * rstd[r] * gv + bv2;
            y = fmaxf(y, 0.f);
            out[(size_t)row * DD + col] = x[(size_t)row * DD + col] + y;
        }
    }
}

// ---------------- launch ----------------

extern "C" void kernel_launch(void* const* d_in, const int* in_sizes, int n_in,
                              void* d_out, int out_size, void* d_ws, size_t ws_size,
                              hipStream_t stream) {
    const float* x  = (const float*)d_in[0];
    const int*   ei = (const int*)d_in[1];
    const float* g1 = (const float*)d_in[2];
    const float* b1 = (const float*)d_in[3];
    const float* g2 = (const float*)d_in[4];
    const float* b2 = (const float*)d_in[5];
    const float* Wq = (const float*)d_in[6];
    const float* bq = (const float*)d_in[7];
    const float* Wk = (const float*)d_in[8];
    const float* bk = (const float*)d_in[9];
    const float* Wv = (const float*)d_in[10];
    const float* bv = (const float*)d_in[11];
    const float* Wo = (const float*)d_in[12];
    const float* bo = (const float*)d_in[13];
    float* out = (float*)d_out;

    int N_ = in_sizes[0] / DD;
    int E_ = in_sizes[1] / 2;
    const int* srcp = ei;
    const int* dstp = ei + E_;

    int nb1 = (E_ + EPB - 1) / EPB;         // stage-1 blocks
    int np  = (N_ + 127) / 128;             // partitions / stage-2 blocks

    char* w = (char*)d_ws;
    float* q   = (float*)w;  w += (size_t)N_ * DD * 4;
    u16* xn    = (u16*)w;    w += (size_t)N_ * DD * 2;
    u16* khv   = (u16*)w;    w += (size_t)N_ * 512 * 2;
    u16* Wt    = (u16*)w;    w += (size_t)1024 * DD * 2;
    int* cnt   = (int*)w;    w += (size_t)N_ * 4;
    int* bkt   = (int*)w;    w += (size_t)N_ * BKT * 4;
    unsigned* stageE = (unsigned*)w; w += (size_t)nb1 * EPB * 4;
    int* stageI      = (int*)w;      w += (size_t)nb1 * (NPM + 1) * 4;
    u16* agg   = xn;   // xn is dead after k_mid; reuse as agg (N x 256 bf16)

    int pre_blocks = nb1 + 64 + (N_ + 3) / 4;

    int nxb = (N_ + 63) / 64;
    int mid_blocks = np + nxb * 3;

    int attn_blocks = ((N_ + 15) / 16) * 8; // 16 nodes per 8-block group (2/wave x 4 waves x 2 subs) x 4 heads
    int Gn = (N_ + 15) / 16;

    k_pre<<<pre_blocks, 256, 0, stream>>>(Wq, Wk, Wv, Wo, Wt, x, g1, b1, N_, xn,
                                          srcp, dstp, E_, stageE, stageI, nb1);
    k_mid<<<mid_blocks, 256, 0, stream>>>(stageE, stageI, nb1, np, cnt, bkt,
                                          xn, Wt, bq, bk, bv, N_, q, khv, E_);
    k_attn<<<attn_blocks, 256, 0, stream>>>(q, khv, cnt, bkt, N_, agg);
    k_out<<<Gn, 256, 0, stream>>>(agg, Wt, bo, g2, b2, x, N_, out);
}

// Round 12
// 181.190 us; speedup vs baseline: 1.0554x; 1.0554x over previous
//
#include <hip/hip_runtime.h>
#include <hip/hip_bf16.h>
#include <math.h>

#define DD 256
#define LN_EPS 1e-5f
#define BKT 128     // fixed bucket slots per destination node (P(deg>128) ~ 0 at E/N=32)
#define EPB 2048    // edges per stage-1 block
#define NPM 256     // max partitions supported (N_ <= 32768); partition = dst >> 7

typedef unsigned short u16;
typedef __attribute__((ext_vector_type(8))) short short8;
typedef __attribute__((ext_vector_type(4))) float floatx4;

__device__ __forceinline__ u16 f2b(float f) {
    __hip_bfloat16 h = __float2bfloat16(f);
    return *reinterpret_cast<u16*>(&h);
}
__device__ __forceinline__ float b2f(unsigned int u) {
    union { unsigned int i; float f; } x;
    x.i = u << 16;
    return x.f;
}

// ---------------- fused preamble: edge partition-sort stage1 | weight transpose+bf16 | LN1 ----

__global__ void __launch_bounds__(256) k_pre(
    const float* __restrict__ Wq, const float* __restrict__ Wk,
    const float* __restrict__ Wv, const float* __restrict__ Wo,
    u16* __restrict__ Wt,
    const float* __restrict__ x, const float* __restrict__ g1, const float* __restrict__ b1,
    int N_, u16* __restrict__ xn,
    const int* __restrict__ src, const int* __restrict__ dst, int E_,
    unsigned* __restrict__ stageE, int* __restrict__ stageI, int nb1) {
    int b = blockIdx.x;
    int t = threadIdx.x;

    if (b < nb1) {                      // ---- stage 1: partition-group edges ----
        __shared__ int h[NPM];
        __shared__ int hs[NPM];
        __shared__ int h2[NPM];
        int e0 = b * EPB;
        int ecnt = E_ - e0; if (ecnt > EPB) ecnt = EPB;
        if (t < NPM) h[t] = 0;
        __syncthreads();
        for (int i = t; i < ecnt; i += 256) {
            int d = dst[e0 + i];
            atomicAdd(&h[d >> 7], 1);           // LDS atomic
        }
        __syncthreads();
        if (t < NPM) hs[t] = h[t];
        __syncthreads();
        for (int off = 1; off < NPM; off <<= 1) {   // Hillis-Steele inclusive scan
            int add = 0;
            if (t < NPM && t >= off) add = hs[t - off];
            __syncthreads();
            if (t < NPM) hs[t] += add;
            __syncthreads();
        }
        if (t < NPM) {
            int ex = hs[t] - h[t];              // exclusive prefix
            h2[t] = ex;
            stageI[b * (NPM + 1) + t] = ex;
            if (t == NPM - 1) stageI[b * (NPM + 1) + NPM] = hs[t];
        }
        __syncthreads();
        for (int i = t; i < ecnt; i += 256) {
            int d = dst[e0 + i];
            int s = src[e0 + i];
            int p = d >> 7;
            int slot = atomicAdd(&h2[p], 1);    // LDS atomic
            int dl = d & 127;
            stageE[(size_t)b * EPB + slot] = (unsigned)((dl << 16) | s);
        }
        return;
    }
    if (b < nb1 + 64) {                 // ---- weight transpose + bf16 convert ----
        __shared__ float tile[64][65];
        int bb = b - nb1;
        int k0 = (bb & 3) * 64;
        int n0 = (bb >> 2) * 64;
        int sel = n0 >> 8;
        const float* W = (sel == 0) ? Wq : (sel == 1) ? Wk : (sel == 2) ? Wv : Wo;
        int ncol0 = n0 & 255;
#pragma unroll
        for (int p = 0; p < 16; p++) {
            int kk = p * 4 + (t >> 6);
            int nn = t & 63;
            tile[kk][nn] = W[(size_t)(k0 + kk) * DD + ncol0 + nn];
        }
        __syncthreads();
#pragma unroll
        for (int p = 0; p < 16; p++) {
            int nn = p * 4 + (t >> 6);
            int kk = t & 63;
            Wt[(size_t)(n0 + nn) * DD + k0 + kk] = f2b(tile[kk][nn]);
        }
        return;
    }
    // ---- LN1: wave per node ----
    int lane = t & 63;
    int node = (b - nb1 - 64) * 4 + (t >> 6);
    if (node >= N_) return;
    size_t base = (size_t)node * DD + lane * 4;
    float4 xv = *(const float4*)&x[base];
    float s = xv.x + xv.y + xv.z + xv.w;
    s += __shfl_xor(s, 1); s += __shfl_xor(s, 2); s += __shfl_xor(s, 4);
    s += __shfl_xor(s, 8); s += __shfl_xor(s, 16); s += __shfl_xor(s, 32);
    float mean = s * (1.f / DD);
    float d0 = xv.x - mean, d1 = xv.y - mean, d2 = xv.z - mean, d3 = xv.w - mean;
    float v = d0 * d0 + d1 * d1 + d2 * d2 + d3 * d3;
    v += __shfl_xor(v, 1); v += __shfl_xor(v, 2); v += __shfl_xor(v, 4);
    v += __shfl_xor(v, 8); v += __shfl_xor(v, 16); v += __shfl_xor(v, 32);
    float rstd = rsqrtf(v * (1.f / DD) + LN_EPS);
    float4 gv = *(const float4*)&g1[lane * 4];
    float4 bv = *(const float4*)&b1[lane * 4];
    uint2 o;
    o.x = (unsigned)f2b(d0 * rstd * gv.x + bv.x) | ((unsigned)f2b(d1 * rstd * gv.y + bv.y) << 16);
    o.y = (unsigned)f2b(d2 * rstd * gv.z + bv.z) | ((unsigned)f2b(d3 * rstd * gv.w + bv.w) << 16);
    *(uint2*)&xn[base] = o;
}

// ---------------- merged: stage-2 bucketize (LDS atomics only) | QKV GEMM ----------------
// khv layout (bf16), per-head INTERLEAVED k/v (r7 layout — best measured):
//   khv[(h*N + node)*128 + (dim>>2)*8 + (dim&3) + (v? 4:0)]
// Per-head block = 2.56MB -> XCD-L2 resident. q stays f32 with 1/sqrt(64) folded.
// Buckets PADDED to a multiple of 32 entries with index 0 (masked by deg in k_attn).

__global__ void __launch_bounds__(256) k_mid(
    const unsigned* __restrict__ stageE, const int* __restrict__ stageI, int nb1, int np,
    int* __restrict__ cnt, int* __restrict__ bkt,
    const u16* __restrict__ xn, const u16* __restrict__ Wt,
    const float* __restrict__ bq, const float* __restrict__ bk, const float* __restrict__ bv,
    int N_, float* __restrict__ q, u16* __restrict__ khv, int E_) {
    int b = blockIdx.x;
    int t = threadIdx.x;

    if (b < np) {                       // ---- stage 2: bucketize partition b ----
        __shared__ int lcnt[128];
        if (t < 128) lcnt[t] = 0;
        __syncthreads();
        int node0 = b << 7;
        for (int bb = t; bb < nb1; bb += 256) {
            int beg = stageI[bb * (NPM + 1) + b];
            int end = stageI[bb * (NPM + 1) + b + 1];
            const unsigned* se = stageE + (size_t)bb * EPB;
            for (int i = beg; i < end; i++) {
                unsigned v = se[i];
                int dl = v >> 16;
                int s = v & 0xffff;
                int sl = atomicAdd(&lcnt[dl], 1);   // LDS atomic
                if (sl < BKT) bkt[(size_t)(node0 + dl) * BKT + sl] = s;
            }
        }
        __syncthreads();
        if (t < 128) {
            int node = node0 + t;
            if (node < N_) {
                int c = lcnt[t]; if (c > BKT) c = BKT;
                cnt[node] = lcnt[t];
                int cap = (c + 31) & ~31; if (cap > BKT) cap = BKT;
                for (int i = c; i < cap; i++)       // pad to mult-of-32 (masked by deg)
                    bkt[(size_t)node * BKT + i] = 0;
            }
        }
        return;
    }

    // ---- QKV GEMM: 64-row x 256-col blocks (kind=q/k/v), wave = one head's 64 cols ----
    int bq_ = b - np;
    int nxb = (N_ + 63) / 64;
    int bx = bq_ % nxb, kind = bq_ / nxb;   // kind: 0=q, 1=k, 2=v
    int w = t >> 6, lane = t & 63;
    int li = lane & 15, quad = lane >> 4;
    int m0 = bx * 64;
    int ncol0 = kind * 256 + w * 64;

    floatx4 acc[4][4];
#pragma unroll
    for (int mi = 0; mi < 4; mi++)
#pragma unroll
        for (int nf = 0; nf < 4; nf++) acc[mi][nf] = (floatx4){0.f, 0.f, 0.f, 0.f};

    const u16* A[4];
#pragma unroll
    for (int mi = 0; mi < 4; mi++) {
        int r = m0 + mi * 16 + li;
        if (r > N_ - 1) r = N_ - 1;
        A[mi] = xn + (size_t)r * DD;
    }
    const u16* B0 = Wt + (size_t)(ncol0 + li) * DD;

    short8 a[4], bb[4];
    int ko = quad * 8;
#pragma unroll
    for (int mi = 0; mi < 4; mi++) a[mi] = *(const short8*)&A[mi][ko];
#pragma unroll
    for (int nf = 0; nf < 4; nf++) bb[nf] = *(const short8*)&B0[(size_t)nf * 16 * DD + ko];

    for (int kk = 0; kk < 8; kk++) {
        short8 an[4], bn[4];
        if (kk < 7) {
            int kon = (kk + 1) * 32 + quad * 8;
#pragma unroll
            for (int mi = 0; mi < 4; mi++) an[mi] = *(const short8*)&A[mi][kon];
#pragma unroll
            for (int nf = 0; nf < 4; nf++) bn[nf] = *(const short8*)&B0[(size_t)nf * 16 * DD + kon];
        }
#pragma unroll
        for (int nf = 0; nf < 4; nf++)
#pragma unroll
            for (int mi = 0; mi < 4; mi++)
                acc[mi][nf] = __builtin_amdgcn_mfma_f32_16x16x32_bf16(a[mi], bb[nf], acc[mi][nf], 0, 0, 0);
        if (kk < 7) {
#pragma unroll
            for (int mi = 0; mi < 4; mi++) a[mi] = an[mi];
#pragma unroll
            for (int nf = 0; nf < 4; nf++) bb[nf] = bn[nf];
        }
    }

    // epilogue: q f32 (0.125 folded); k/v interleaved bf16
#pragma unroll
    for (int nf = 0; nf < 4; nf++) {
        int c = ncol0 + nf * 16 + li;            // global col
        float bias;
        if (kind == 0)      bias = bq[c];
        else if (kind == 1) bias = bk[c - 256];
        else                bias = bv[c - 512];
        int cc = (kind == 0) ? c : (c - (kind == 1 ? 256 : 512));  // 0..255
        int h = cc >> 6, dim = cc & 63;
#pragma unroll
        for (int mi = 0; mi < 4; mi++) {
#pragma unroll
            for (int r = 0; r < 4; r++) {
                int row = m0 + mi * 16 + quad * 4 + r;
                if (row >= N_) continue;
                float val = acc[mi][nf][r] + bias;
                if (kind == 0) {
                    q[(size_t)row * DD + c] = val * 0.125f;  // fold 1/sqrt(64)
                } else {
                    size_t idx = ((size_t)h * N_ + row) * 128
                               + (dim >> 2) * 8 + (dim & 3) + (kind == 2 ? 4 : 0);
                    khv[idx] = f2b(val);
                }
            }
        }
    }
}

// ---------------- attention: head-split + XCD-pinned, 1 node/wave, 8-deep pipeline ----
// BEST MEASURED STRUCTURE (r7 = 181.0, r10 = 181.2 wall). Reverted after the
// r11 dual-chain regression (50us, occupancy 34%). Ledger of failed levers on
// this kernel: MFMA scores (r8, sync point), 32-edge single window (r9, one
// window/wave), dual independent chains (r11, guard serialization + VGPR).
// Conclusion: ~40us here is the XCD-L2 random-gather service-rate wall
// (~8 TB/s effective on 256B rows); FETCH is compulsory-only (~20MB).
// block b: XCD = b%8, head h = (b&7)>>1 -> per-head khv (2.56MB) L2-resident.
// Wave = 4 quad-slots x 16 lanes, ONE node; 32 edges/iter, 8 outstanding 256B
// row-gathers; indices via broadcast int4 (buckets padded to mult-of-32).

__global__ void __launch_bounds__(256) k_attn(
    const float* __restrict__ q, const u16* __restrict__ khv,
    const int* __restrict__ cnt, const int* __restrict__ bkt,
    int N_, u16* __restrict__ agg) {
    int t = threadIdx.x;
    int w = t >> 6, lane = t & 63;
    int li = lane & 15, quad = lane >> 4;
    int b = blockIdx.x;
    int g = b >> 3;
    int h = (b & 7) >> 1;
    int sub = b & 1;
    int node = g * 8 + sub * 4 + w;
    if (node >= N_) return;
    const u16* kvh = khv + (size_t)h * N_ * 128;
    size_t kvoff = (size_t)li * 8;

    int deg = cnt[node]; if (deg > BKT) deg = BKT;
    u16* ao = agg + (size_t)node * DD + h * 64 + li * 4;
    if (deg == 0) {
        if (quad == 0) { uint2 z; z.x = 0u; z.y = 0u; *(uint2*)ao = z; }
        return;
    }
    const int* eb = bkt + (size_t)node * BKT;
    float4 qv = *(const float4*)&q[(size_t)node * DD + h * 64 + li * 4];

    float l = 0.f, ax = 0.f, ay = 0.f, az = 0.f, aw = 0.f;

    // window-0 indices: slots quad*8..+8 (padded -> always valid loads, broadcast per quad)
    int4 sA = *(const int4*)&eb[quad * 8];
    int4 sB = *(const int4*)&eb[quad * 8 + 4];

    for (int e = 0; e < deg; e += 32) {
        uint4 p[8];
        p[0] = *(const uint4*)&kvh[(size_t)sA.x * 128 + kvoff];
        p[1] = *(const uint4*)&kvh[(size_t)sA.y * 128 + kvoff];
        p[2] = *(const uint4*)&kvh[(size_t)sA.z * 128 + kvoff];
        p[3] = *(const uint4*)&kvh[(size_t)sA.w * 128 + kvoff];
        p[4] = *(const uint4*)&kvh[(size_t)sB.x * 128 + kvoff];
        p[5] = *(const uint4*)&kvh[(size_t)sB.y * 128 + kvoff];
        p[6] = *(const uint4*)&kvh[(size_t)sB.z * 128 + kvoff];
        p[7] = *(const uint4*)&kvh[(size_t)sB.w * 128 + kvoff];

        int en = e + 32;
        if (en < deg) {                 // wave-uniform: prefetch next window's indices
            sA = *(const int4*)&eb[en + quad * 8];
            sB = *(const int4*)&eb[en + quad * 8 + 4];
        }

#pragma unroll
        for (int d = 0; d < 8; d++) {
            bool valid = (e + quad * 8 + d) < deg;
            float s = qv.x * b2f(p[d].x & 0xffff) + qv.y * b2f(p[d].x >> 16)
                    + qv.z * b2f(p[d].y & 0xffff) + qv.w * b2f(p[d].y >> 16);
            s += __shfl_xor(s, 1); s += __shfl_xor(s, 2);
            s += __shfl_xor(s, 4); s += __shfl_xor(s, 8);   // reduce within 16-lane group
            float pe = valid ? __expf(s) : 0.f;
            l += pe;
            ax += pe * b2f(p[d].z & 0xffff);
            ay += pe * b2f(p[d].z >> 16);
            az += pe * b2f(p[d].w & 0xffff);
            aw += pe * b2f(p[d].w >> 16);
        }
    }
    // combine the 4 quad-slot groups (reduce over quad: lanes ^16, ^32)
    l  += __shfl_xor(l, 16);  l  += __shfl_xor(l, 32);
    ax += __shfl_xor(ax, 16); ax += __shfl_xor(ax, 32);
    ay += __shfl_xor(ay, 16); ay += __shfl_xor(ay, 32);
    az += __shfl_xor(az, 16); az += __shfl_xor(az, 32);
    aw += __shfl_xor(aw, 16); aw += __shfl_xor(aw, 32);
    float invl = 1.f / l;
    if (quad == 0) {
        uint2 o;
        o.x = (unsigned)f2b(ax * invl) | ((unsigned)f2b(ay * invl) << 16);
        o.y = (unsigned)f2b(az * invl) | ((unsigned)f2b(aw * invl) << 16);
        *(uint2*)ao = o;
    }
}

// ---------------- out-GEMM + LN2 + relu + residual: 16 rows/block ----------------

__global__ void __launch_bounds__(256) k_out(
    const u16* __restrict__ agg, const u16* __restrict__ Wt, const float* __restrict__ bo,
    const float* __restrict__ g2, const float* __restrict__ b2,
    const float* __restrict__ x, int N_, float* __restrict__ out) {
    __shared__ float wsum[4][16];
    __shared__ float wvar[4][16];
    int t = threadIdx.x;
    int w = t >> 6, lane = t & 63;
    int li = lane & 15, quad = lane >> 4;
    int m0 = blockIdx.x * 16;

    int ar = m0 + li; if (ar > N_ - 1) ar = N_ - 1;
    const u16* A0 = agg + (size_t)ar * DD;
    const u16* B0 = Wt + (size_t)(768 + w * 64 + li) * DD;

    floatx4 acc[4];
#pragma unroll
    for (int nf = 0; nf < 4; nf++) acc[nf] = (floatx4){0.f, 0.f, 0.f, 0.f};

#pragma unroll 2
    for (int kk = 0; kk < 8; kk++) {
        int ko = kk * 32 + quad * 8;
        short8 a = *(const short8*)&A0[ko];
#pragma unroll
        for (int nf = 0; nf < 4; nf++) {
            short8 bfrag = *(const short8*)&B0[(size_t)nf * 16 * DD + ko];
            acc[nf] = __builtin_amdgcn_mfma_f32_16x16x32_bf16(a, bfrag, acc[nf], 0, 0, 0);
        }
    }

#pragma unroll
    for (int nf = 0; nf < 4; nf++) {
        float bb = bo[w * 64 + nf * 16 + li];
#pragma unroll
        for (int r = 0; r < 4; r++) acc[nf][r] += bb;
    }

    // LN2: per-row partial sums over this wave's 64 cols, then cross-wave via LDS
#pragma unroll
    for (int r = 0; r < 4; r++) {
        float s = acc[0][r] + acc[1][r] + acc[2][r] + acc[3][r];
        s += __shfl_xor(s, 1); s += __shfl_xor(s, 2);
        s += __shfl_xor(s, 4); s += __shfl_xor(s, 8);
        if (li == 0) wsum[w][quad * 4 + r] = s;
    }
    __syncthreads();
    float mean[4];
#pragma unroll
    for (int r = 0; r < 4; r++) {
        int rl = quad * 4 + r;
        mean[r] = (wsum[0][rl] + wsum[1][rl] + wsum[2][rl] + wsum[3][rl]) * (1.f / DD);
    }
#pragma unroll
    for (int r = 0; r < 4; r++) {
        float vs = 0.f;
#pragma unroll
        for (int nf = 0; nf < 4; nf++) {
            float d = acc[nf][r] - mean[r];
            vs += d * d;
        }
        vs += __shfl_xor(vs, 1); vs += __shfl_xor(vs, 2);
        vs += __shfl_xor(vs, 4); vs += __shfl_xor(vs, 8);
        if (li == 0) wvar[w][quad * 4 + r] = vs;
    }
    __syncthreads();
    float rstd[4];
#pragma unroll
    for (int r = 0; r < 4; r++) {
        int rl = quad * 4 + r;
        rstd[r] = rsqrtf((wvar[0][rl] + wvar[1][rl] + wvar[2][rl] + wvar[3][rl]) * (1.f / DD) + LN_EPS);
    }

#pragma unroll
    for (int nf = 0; nf < 4; nf++) {
        int col = w * 64 + nf * 16 + li;
        float gv = g2[col], bv2 = b2[col];
#pragma unroll
        for (int r = 0; r < 4; r++) {
            int row = m0 + quad * 4 + r;
            if (row >= N_) continue;
            float y = (acc[nf][r] - mean[r]) * rstd[r] * gv + bv2;
            y = fmaxf(y, 0.f);
            out[(size_t)row * DD + col] = x[(size_t)row * DD + col] + y;
        }
    }
}

// ---------------- launch ----------------

extern "C" void kernel_launch(void* const* d_in, const int* in_sizes, int n_in,
                              void* d_out, int out_size, void* d_ws, size_t ws_size,
                              hipStream_t stream) {
    const float* x  = (const float*)d_in[0];
    const int*   ei = (const int*)d_in[1];
    const float* g1 = (const float*)d_in[2];
    const float* b1 = (const float*)d_in[3];
    const float* g2 = (const float*)d_in[4];
    const float* b2 = (const float*)d_in[5];
    const float* Wq = (const float*)d_in[6];
    const float* bq = (const float*)d_in[7];
    const float* Wk = (const float*)d_in[8];
    const float* bk = (const float*)d_in[9];
    const float* Wv = (const float*)d_in[10];
    const float* bv = (const float*)d_in[11];
    const float* Wo = (const float*)d_in[12];
    const float* bo = (const float*)d_in[13];
    float* out = (float*)d_out;

    int N_ = in_sizes[0] / DD;
    int E_ = in_sizes[1] / 2;
    const int* srcp = ei;
    const int* dstp = ei + E_;

    int nb1 = (E_ + EPB - 1) / EPB;         // stage-1 blocks
    int np  = (N_ + 127) / 128;             // partitions / stage-2 blocks

    char* w = (char*)d_ws;
    float* q   = (float*)w;  w += (size_t)N_ * DD * 4;
    u16* xn    = (u16*)w;    w += (size_t)N_ * DD * 2;
    u16* khv   = (u16*)w;    w += (size_t)N_ * 512 * 2;
    u16* Wt    = (u16*)w;    w += (size_t)1024 * DD * 2;
    int* cnt   = (int*)w;    w += (size_t)N_ * 4;
    int* bkt   = (int*)w;    w += (size_t)N_ * BKT * 4;
    unsigned* stageE = (unsigned*)w; w += (size_t)nb1 * EPB * 4;
    int* stageI      = (int*)w;      w += (size_t)nb1 * (NPM + 1) * 4;
    u16* agg   = xn;   // xn is dead after k_mid; reuse as agg (N x 256 bf16)

    int pre_blocks = nb1 + 64 + (N_ + 3) / 4;

    int nxb = (N_ + 63) / 64;
    int mid_blocks = np + nxb * 3;

    int attn_blocks = ((N_ + 7) / 8) * 8;   // 8 nodes per 8-block group (4 nodes x 2 subs) x 4 heads
    int Gn = (N_ + 15) / 16;

    k_pre<<<pre_blocks, 256, 0, stream>>>(Wq, Wk, Wv, Wo, Wt, x, g1, b1, N_, xn,
                                          srcp, dstp, E_, stageE, stageI, nb1);
    k_mid<<<mid_blocks, 256, 0, stream>>>(stageE, stageI, nb1, np, cnt, bkt,
                                          xn, Wt, bq, bk, bv, N_, q, khv, E_);
    k_attn<<<attn_blocks, 256, 0, stream>>>(q, khv, cnt, bkt, N_, agg);
    k_out<<<Gn, 256, 0, stream>>>(agg, Wt, bo, g2, b2, x, N_, out);
}